// Round 2
// baseline (5838.344 us; speedup 1.0000x reference)
//
#include <hip/hip_runtime.h>
#include <hip/hip_bf16.h>

// GRU-imputation scan (B=128,T=128,D=128,H=1024,L=3), f32 in/out.
// Round 6 (resubmit after infra failures): IC phase fused into L0. Each step
// is 3 grid-barrier phases (L0, L1, L2) instead of 4. imp/comp for step t-1
// are computed redundantly per block at the top of step t's L0 phase from the
// already-staged hA slice (lds_h), scattered directly into lds_c fragment
// layout; comp global buffer and its coherent traffic are eliminated.
// Out writes distributed by jpair.

typedef __hip_bfloat16 bf16;
typedef unsigned int u32;
typedef unsigned short u16;
typedef __attribute__((ext_vector_type(8))) short v8bf;   // 8 x bf16 (16B)
typedef __attribute__((ext_vector_type(4))) float v4f;    // MFMA C/D
typedef __attribute__((ext_vector_type(4))) u32 v4u;

#define SC __HIP_MEMORY_SCOPE_AGENT

__device__ __forceinline__ float bf2f(bf16 v){ return __bfloat162float(v); }
__device__ __forceinline__ bf16 f2bf(float v){ return __float2bfloat16(v); }
__device__ __forceinline__ float sigm(float x){ return 1.f/(1.f + __expf(-x)); }
__device__ __forceinline__ float tanh_(float x){
  float a = fminf(fmaxf(x, -15.f), 15.f);
  float t = __expf(2.f*a);
  return (t-1.f)/(t+1.f);
}
__device__ __forceinline__ v8bf ldv(const bf16* p){ return *reinterpret_cast<const v8bf*>(p); }
__device__ __forceinline__ void vdrain(){ asm volatile("s_waitcnt vmcnt(0)" ::: "memory"); }

// ---- device-coherent (LLC) accesses: bypass L1+L2 via sc0 sc1 ----
__device__ __forceinline__ void ldx4_coh(const bf16* p0, const bf16* p1,
                                         const bf16* p2, const bf16* p3,
                                         v4u& r0, v4u& r1, v4u& r2, v4u& r3){
  asm volatile(
    "global_load_dwordx4 %0, %4, off sc0 sc1\n\t"
    "global_load_dwordx4 %1, %5, off sc0 sc1\n\t"
    "global_load_dwordx4 %2, %6, off sc0 sc1\n\t"
    "global_load_dwordx4 %3, %7, off sc0 sc1\n\t"
    "s_waitcnt vmcnt(0)"
    : "=&v"(r0), "=&v"(r1), "=&v"(r2), "=&v"(r3)
    : "v"(p0), "v"(p1), "v"(p2), "v"(p3)
    : "memory");
}
__device__ __forceinline__ void st2_coh(bf16* p, bf16 v){
  u32 vv = (u32)__builtin_bit_cast(u16, v);
  asm volatile("global_store_short %0, %1, off sc0 sc1" :: "v"(p), "v"(vv) : "memory");
}

// ---- per-group barrier: 32 arrivals, relaxed atomics, no cache ops ----
__device__ __forceinline__ void gbar2(u32* ctr, u32* ep, u32 target){
  __syncthreads();
  if (threadIdx.x == 0){
    vdrain();                                        // all coherent stores at LLC
    u32 a = __hip_atomic_fetch_add(ctr, 1u, __ATOMIC_RELAXED, SC);
    if (a == 31u){
      __hip_atomic_store(ctr, 0u, __ATOMIC_RELAXED, SC);
      vdrain();                                      // reset visible before epoch++
      __hip_atomic_fetch_add(ep, 1u, __ATOMIC_RELAXED, SC);
    }
    while (__hip_atomic_load(ep, __ATOMIC_RELAXED, SC) < target){
      __builtin_amdgcn_s_sleep(1);
    }
  }
  __syncthreads();
}

// =================================================================
// Packing kernels (unchanged; validated).
// Fragment unit = 64 lanes x 8 bf16; lane's 8 elems =
//   W[row(j,lane&15)][kk*32 + ((lane>>4)&3)*8 + e]
// =================================================================
__global__ void pack_upper_k(const float* __restrict__ Wih, const float* __restrict__ Whh,
                             bf16* __restrict__ dst){
  int tid = blockIdx.x*256 + threadIdx.x;          // 1,048,576
  int lane = tid & 63;
  int u    = tid >> 6;
  int kk   = u & 31;
  int j    = (u >> 5) & 63;
  int s    = (u >> 11) & 3;
  int l    = u >> 13;
  int n    = j*16 + (lane & 15);
  int k    = kk*32 + ((lane>>4)&3)*8;
  int row  = (s==0) ? n : (s==1 ? 1024+n : 2048+n);
  size_t src = ((size_t)l*3072 + row)*1024 + k;
  size_t o = (size_t)tid*8;
  #pragma unroll
  for (int e=0;e<8;e++){
    float v;
    if (s < 2)      v = Wih[src+e] + Whh[src+e];
    else if (s==2)  v = Wih[src+e];
    else            v = Whh[src+e];
    dst[o+e] = f2bf(v);
  }
}
__global__ void pack_l0h_k(const float* __restrict__ Whh0, bf16* __restrict__ dst){
  int tid = blockIdx.x*256 + threadIdx.x;          // 393,216
  int lane = tid & 63;
  int u  = tid >> 6;
  int kk = u & 31;
  int j  = (u >> 5) & 63;
  int g  = u >> 11;
  int row = g*1024 + j*16 + (lane&15);
  int k   = kk*32 + ((lane>>4)&3)*8;
  size_t src = (size_t)row*1024 + k;
  size_t o = (size_t)tid*8;
  #pragma unroll
  for (int e=0;e<8;e++) dst[o+e] = f2bf(Whh0[src+e]);
}
__global__ void pack_l0x_k(const float* __restrict__ Wih0, bf16* __restrict__ dst){
  int tid = blockIdx.x*256 + threadIdx.x;          // 49,152
  int lane = tid & 63;
  int u  = tid >> 6;
  int kk = u & 3;
  int j  = (u >> 2) & 63;
  int g  = u >> 8;
  int row = g*1024 + j*16 + (lane&15);
  int k   = kk*32 + ((lane>>4)&3)*8;
  size_t src = (size_t)row*128 + k;
  size_t o = (size_t)tid*8;
  #pragma unroll
  for (int e=0;e<8;e++) dst[o+e] = f2bf(Wih0[src+e]);
}
__global__ void pack_imp_k(const float* __restrict__ Wp, bf16* __restrict__ dst){
  int tid = blockIdx.x*256 + threadIdx.x;          // 16,384
  int lane = tid & 63;
  int u  = tid >> 6;
  int kk = u & 31;
  int jj = u >> 5;
  int row = jj*16 + (lane&15);
  int k   = kk*32 + ((lane>>4)&3)*8;
  size_t src = (size_t)row*1024 + k;
  size_t o = (size_t)tid*8;
  #pragma unroll
  for (int e=0;e<8;e++) dst[o+e] = f2bf(Wp[src+e]);
}
__global__ void init_pk(u32* __restrict__ bar, bf16* __restrict__ h3){
  int tid = blockIdx.x*256 + threadIdx.x;          // 393,216
  if (tid < 1024) bar[tid] = 0u;
  h3[tid] = f2bf(0.f);                             // hA, hB, hC = 0
}

// =================================================================
// Staging: 32 rows x 1024 cols of h (row stride 1024) -> fragment-ordered
// LDS (64 KB). unit = kk*2 + half (kk=K-chunk 0..31, half=row half).
// chunk-in-unit = lane. Conflict-free ds_write/ds_read.
// =================================================================
__device__ __forceinline__ void stage_h(const bf16* __restrict__ src_rg, bf16* lds_h,
                                        int wave, int lane){
  const int sh = wave & 1, si = (wave >> 1) & 7;
  const int l15 = lane & 15, quad = lane >> 4;
  const bf16* g = src_rg + (size_t)(sh*16 + l15)*1024 + si*32 + quad*8;
  v4u r0,r1,r2,r3;
  ldx4_coh(g, g+256, g+512, g+768, r0,r1,r2,r3);
  bf16* d = lds_h + ((size_t)wave*64 + lane)*8;
  *(v4u*)(d)         = r0;
  *(v4u*)(d + 8192)  = r1;
  *(v4u*)(d + 16384) = r2;
  *(v4u*)(d + 24576) = r3;
}
// A-fragment from staged LDS: rows half*16+l15, K-chunk kk
__device__ __forceinline__ v8bf afrag(const bf16* lds_h, int kk, int ah, int lane){
  return ldv(lds_h + ((size_t)(kk*2+ah)*64 + lane)*8);
}
// scalar element (rl, colh) from staged LDS
__device__ __forceinline__ float hp_lds(const bf16* lds_h, int rl, int colh){
  int kk = colh >> 5, q = (colh >> 3) & 3, e = colh & 7;
  int ah = rl >> 4, lr = rl & 15;
  return bf2f(lds_h[((size_t)(kk*2+ah)*64 + q*16 + lr)*8 + e]);
}

#define MFMA(a,b,c) __builtin_amdgcn_mfma_f32_16x16x32_bf16((a),(b),(c),0,0,0)

// =================================================================
// Main persistent kernel: 128 blocks x 1024 threads (16 waves).
// bid: leaf=bid&7 (XCD affinity for weights), up=bid>>3: rg=up&3 (row group),
// jpair = leaf*4 + (up>>2)  (32 output cols).
// 3 grid-barrier phases per step: L0 (with fused IC for step t-1), L1, L2.
// =================================================================
__global__ __launch_bounds__(1024, 4) void gru_pk(
  const float* __restrict__ x, const float* __restrict__ masks,
  const float* __restrict__ bih0, const float* __restrict__ bhh0,
  const float* __restrict__ bihR, const float* __restrict__ bhhR,
  const float* __restrict__ bp,
  const bf16* __restrict__ packU, const bf16* __restrict__ packL0h,
  const bf16* __restrict__ packL0x, const bf16* __restrict__ packImp,
  bf16* hA, bf16* hB, bf16* hC,
  u32* bar, float* out)
{
  const int tid  = threadIdx.x;
  const int lane = tid & 63;
  const int wave = tid >> 6;           // 0..15
  const int l15  = lane & 15;
  const int quad = lane >> 4;
  const int bid  = blockIdx.x;
  const int leaf = bid & 7;
  const int up   = bid >> 3;           // 0..15
  const int rg   = up & 3;             // row group
  const int jpair= leaf*4 + (up >> 2); // 0..31
  const int rg32 = rg * 32;
  u32* ctr = bar + rg*128;
  u32* ep  = bar + rg*128 + 64;

  __shared__ bf16 lds_h[32768];        // 64 KB staged h slice
  __shared__ bf16 lds_c[4096];         // 8 KB staged comp slice
  __shared__ float lds2[18*512];       // 36 KB pre-activation partials
  u32 bc = 0;

  #pragma unroll 1
  for (int t = 0; t < 128; ++t){
    // ====== L0: fused IC(t-1) + hB = GRU0(input=comp(t-1), hidden=hA) ======
    {
      stage_h(hA + (size_t)rg32*1024, lds_h, wave, lane);
      __syncthreads();
      // ---- fused IC: build comp slice into lds_c ----
      if (t == 0){
        // comp(-1) = x[:, 0, :]
        if (wave < 8){
          const int sh = wave & 1, skk = wave >> 1;
          const float* g = x + (size_t)(rg32 + sh*16 + l15)*16384 + (size_t)skk*32 + quad*8;
          bf16* d = lds_c + ((size_t)wave*64 + lane)*8;
          #pragma unroll
          for (int e=0;e<8;e++) d[e] = f2bf(g[e]);
        }
      } else {
        // imp(t-1)[32,128] = lds_h(hA slice) @ Wp^T + bp, computed redundantly.
        // wave w -> output tile (ah = w&1 row half, dj = w>>1 col tile of 16)
        const int ah = wave & 1, dj = wave >> 1;
        v4f acc = {0.f,0.f,0.f,0.f};
        const bf16* wp = packImp + ((size_t)(dj*32))*512 + lane*8;
        #pragma unroll
        for (int kk=0;kk<32;++kk){
          acc = MFMA(afrag(lds_h, kk, ah, lane), ldv(wp + (size_t)kk*512), acc);
        }
        const int d   = dj*16 + l15;
        const int tm  = t - 1;
        const int kkc = d >> 5, qc = (d >> 3) & 3, ec = d & 7;
        bf16* cbase = lds_c + ((size_t)(kkc*2 + ah)*64 + qc*16)*8 + ec;
        const bool wr = ((d >> 2) == jpair);      // unique writer per 4 cols
        const float bpd = bp[d];
        #pragma unroll
        for (int r=0;r<4;r++){
          const int rl  = ah*16 + quad*4 + r;
          const int row = rg32 + rl;
          float imp = acc[r] + bpd;
          float m   = masks[row*128 + tm];
          float xv  = x[((size_t)row*128 + tm)*128 + d];
          float cv  = m*xv + (1.f - m)*imp;
          cbase[(size_t)(quad*4 + r)*8] = f2bf(cv);
          if (wr){
            size_t o = ((size_t)row*127 + tm)*128 + d;
            out[131072 + o]  = cv;    // completed
            out[2211840 + o] = imp;   // imputed
          }
        }
      }
      __syncthreads();
      // ---- main L0 matmuls ----
      if (wave < 12){
        const int g = wave % 3, jsub = (wave/3) & 1, ksec = wave/6;
        const int j = jpair*2 + jsub;
        v4f a0 = {0.f,0.f,0.f,0.f}, a1 = {0.f,0.f,0.f,0.f};
        const bf16* wp = packL0h + ((size_t)((g*64 + j)*32 + ksec*16))*512 + lane*8;
        #pragma unroll
        for (int i=0;i<16;++i){
          int kk = ksec*16 + i;
          v8bf wf = ldv(wp + (size_t)i*512);
          a0 = MFMA(afrag(lds_h, kk, 0, lane), wf, a0);
          a1 = MFMA(afrag(lds_h, kk, 1, lane), wf, a1);
        }
        #pragma unroll
        for (int r=0;r<4;r++){
          lds2[(wave*32 + quad*4 + r)*16 + l15]      = a0[r];
          lds2[(wave*32 + 16 + quad*4 + r)*16 + l15] = a1[r];
        }
      } else if (wave < 15){
        const int g = wave - 12;
        #pragma unroll
        for (int jsub=0;jsub<2;++jsub){
          const int j = jpair*2 + jsub;
          v4f a0 = {0.f,0.f,0.f,0.f}, a1 = {0.f,0.f,0.f,0.f};
          const bf16* wp = packL0x + ((size_t)((g*64 + j)*4))*512 + lane*8;
          #pragma unroll
          for (int i=0;i<4;++i){
            v8bf wf = ldv(wp + (size_t)i*512);
            a0 = MFMA(ldv(lds_c + ((size_t)(i*2+0)*64 + lane)*8), wf, a0);
            a1 = MFMA(ldv(lds_c + ((size_t)(i*2+1)*64 + lane)*8), wf, a1);
          }
          const int slot = 12 + g*2 + jsub;
          #pragma unroll
          for (int r=0;r<4;r++){
            lds2[(slot*32 + quad*4 + r)*16 + l15]      = a0[r];
            lds2[(slot*32 + 16 + quad*4 + r)*16 + l15] = a1[r];
          }
        }
      }
      __syncthreads();
      {
        const int rl = tid >> 5, c2 = tid & 31;
        const int jsub = c2 >> 4, c = c2 & 15;
        const int col = jpair*32 + c2;
        float ghr = lds2[((0+jsub*3)*32+rl)*16+c] + lds2[((6+jsub*3)*32+rl)*16+c];
        float ghz = lds2[((1+jsub*3)*32+rl)*16+c] + lds2[((7+jsub*3)*32+rl)*16+c];
        float ghn = lds2[((2+jsub*3)*32+rl)*16+c] + lds2[((8+jsub*3)*32+rl)*16+c];
        float gir = lds2[((12+jsub)*32+rl)*16+c];
        float giz = lds2[((14+jsub)*32+rl)*16+c];
        float gin = lds2[((16+jsub)*32+rl)*16+c];
        float rgg = sigm(gir + bih0[col]      + ghr + bhh0[col]);
        float zg  = sigm(giz + bih0[1024+col] + ghz + bhh0[1024+col]);
        float nv  = tanh_(gin + bih0[2048+col] + rgg*(ghn + bhh0[2048+col]));
        float hp  = hp_lds(lds_h, rl, col);
        st2_coh(hB + (size_t)(rg32+rl)*1024 + col, f2bf((1.f - zg)*nv + zg*hp));
        vdrain();
      }
      gbar2(ctr, ep, ++bc);
    }

    // ================= L1 / L2: upper layers =================
    #pragma unroll 1
    for (int lay = 0; lay < 2; ++lay){
      const bf16* src = lay ? hC : hB;
      bf16*       dst = lay ? hA : hC;
      const bf16* packL = packU + (size_t)lay*4194304;
      const float* bi = bihR + lay*3072;
      const float* bh = bhhR + lay*3072;
      float* out_h = (lay == 1 && t == 127) ? out : nullptr;

      stage_h(src + (size_t)rg32*1024, lds_h, wave, lane);
      __syncthreads();
      {
        const int s = wave & 3, jsub = (wave>>2) & 1, ksec = wave >> 3;
        const int j = jpair*2 + jsub;
        v4f a0 = {0.f,0.f,0.f,0.f}, a1 = {0.f,0.f,0.f,0.f};
        const bf16* wp = packL + ((size_t)((s*64 + j)*32 + ksec*16))*512 + lane*8;
        #pragma unroll
        for (int i=0;i<16;++i){
          int kk = ksec*16 + i;
          v8bf wf = ldv(wp + (size_t)i*512);
          a0 = MFMA(afrag(lds_h, kk, 0, lane), wf, a0);
          a1 = MFMA(afrag(lds_h, kk, 1, lane), wf, a1);
        }
        #pragma unroll
        for (int r=0;r<4;r++){
          lds2[(wave*32 + quad*4 + r)*16 + l15]      = a0[r];
          lds2[(wave*32 + 16 + quad*4 + r)*16 + l15] = a1[r];
        }
      }
      __syncthreads();
      {
        const int rl = tid >> 5, c2 = tid & 31;
        const int jsub = c2 >> 4, c = c2 & 15;
        const int col = jpair*32 + c2;
        // slot(s,jsub,ksec) = s + jsub*4 + ksec*8
        float pr  = lds2[((0+jsub*4)*32+rl)*16+c] + lds2[((8+jsub*4)*32+rl)*16+c];
        float pz  = lds2[((1+jsub*4)*32+rl)*16+c] + lds2[((9+jsub*4)*32+rl)*16+c];
        float pin = lds2[((2+jsub*4)*32+rl)*16+c] + lds2[((10+jsub*4)*32+rl)*16+c];
        float phn = lds2[((3+jsub*4)*32+rl)*16+c] + lds2[((11+jsub*4)*32+rl)*16+c];
        float rgg = sigm(pr + bi[col] + bh[col]);
        float zg  = sigm(pz + bi[1024+col] + bh[1024+col]);
        float nv  = tanh_(pin + bi[2048+col] + rgg*(phn + bh[2048+col]));
        float hp  = hp_lds(lds_h, rl, col);
        float hv  = (1.f - zg)*nv + zg*hp;
        st2_coh(dst + (size_t)(rg32+rl)*1024 + col, f2bf(hv));
        if (out_h) out_h[(size_t)(rg32+rl)*1024 + col] = hv;
        vdrain();
      }
      gbar2(ctr, ep, ++bc);
    }
  }
}

// ---------------- host ----------------
extern "C" void kernel_launch(void* const* d_in, const int* in_sizes, int n_in,
                              void* d_out, int out_size, void* d_ws, size_t ws_size,
                              hipStream_t stream)
{
  (void)in_sizes; (void)n_in; (void)out_size; (void)ws_size;
  const float* x     = (const float*)d_in[0];
  const float* masks = (const float*)d_in[1];
  const float* Wih0  = (const float*)d_in[2];
  const float* Whh0  = (const float*)d_in[3];
  const float* bih0  = (const float*)d_in[4];
  const float* bhh0  = (const float*)d_in[5];
  const float* WihR  = (const float*)d_in[6];
  const float* WhhR  = (const float*)d_in[7];
  const float* bihR  = (const float*)d_in[8];
  const float* bhhR  = (const float*)d_in[9];
  const float* Wp    = (const float*)d_in[10];
  const float* bp    = (const float*)d_in[11];
  float* out = (float*)d_out;

  // ws: bar u32[1024] | hA hB hC (bf16 131072 ea) | packed weights
  u32*  bar     = (u32*)d_ws;
  bf16* hA      = (bf16*)((char*)d_ws + 4096);
  bf16* hB      = hA + 131072;
  bf16* hC      = hB + 131072;
  bf16* packU   = hC + 131072;         // 8,388,608 elems
  bf16* packL0h = packU + 8388608;     // 3,145,728
  bf16* packL0x = packL0h + 3145728;   // 393,216
  bf16* packImp = packL0x + 393216;    // 131,072

  hipLaunchKernelGGL(init_pk,      dim3(1536), dim3(256), 0, stream, bar, hA);
  hipLaunchKernelGGL(pack_upper_k, dim3(4096), dim3(256), 0, stream, WihR, WhhR, packU);
  hipLaunchKernelGGL(pack_l0h_k,   dim3(1536), dim3(256), 0, stream, Whh0, packL0h);
  hipLaunchKernelGGL(pack_l0x_k,   dim3(192),  dim3(256), 0, stream, Wih0, packL0x);
  hipLaunchKernelGGL(pack_imp_k,   dim3(64),   dim3(256), 0, stream, Wp, packImp);
  hipLaunchKernelGGL(gru_pk,       dim3(128),  dim3(1024), 0, stream,
      x, masks, bih0, bhh0, bihR, bhhR, bp,
      packU, packL0h, packL0x, packImp, hA, hB, hC, bar, out);
}

// Round 3
// 5699.498 us; speedup vs baseline: 1.0244x; 1.0244x over previous
//
#include <hip/hip_runtime.h>
#include <hip/hip_bf16.h>

// GRU-imputation scan (B=128,T=128,D=128,H=1024,L=3), f32 in/out.
// Round 7: flag-array barrier. Each block stores its epoch to its own slot
// (no atomic RMW serialization); wave 0 of every block polls all 32 slots of
// its group with ONE coalesced 128B load (lane i -> slot i&31) + __all ballot.
// Also: fused-IC imp MFMA chain split into 2 independent accumulators.
// Structure otherwise identical to round 6 (3 phases/step, IC fused into L0).

typedef __hip_bfloat16 bf16;
typedef unsigned int u32;
typedef unsigned short u16;
typedef __attribute__((ext_vector_type(8))) short v8bf;   // 8 x bf16 (16B)
typedef __attribute__((ext_vector_type(4))) float v4f;    // MFMA C/D
typedef __attribute__((ext_vector_type(4))) u32 v4u;

#define SC __HIP_MEMORY_SCOPE_AGENT

__device__ __forceinline__ float bf2f(bf16 v){ return __bfloat162float(v); }
__device__ __forceinline__ bf16 f2bf(float v){ return __float2bfloat16(v); }
__device__ __forceinline__ float sigm(float x){ return 1.f/(1.f + __expf(-x)); }
__device__ __forceinline__ float tanh_(float x){
  float a = fminf(fmaxf(x, -15.f), 15.f);
  float t = __expf(2.f*a);
  return (t-1.f)/(t+1.f);
}
__device__ __forceinline__ v8bf ldv(const bf16* p){ return *reinterpret_cast<const v8bf*>(p); }
__device__ __forceinline__ void vdrain(){ asm volatile("s_waitcnt vmcnt(0)" ::: "memory"); }

// ---- device-coherent (LLC) accesses: bypass L1+L2 via sc0 sc1 ----
__device__ __forceinline__ void ldx4_coh(const bf16* p0, const bf16* p1,
                                         const bf16* p2, const bf16* p3,
                                         v4u& r0, v4u& r1, v4u& r2, v4u& r3){
  asm volatile(
    "global_load_dwordx4 %0, %4, off sc0 sc1\n\t"
    "global_load_dwordx4 %1, %5, off sc0 sc1\n\t"
    "global_load_dwordx4 %2, %6, off sc0 sc1\n\t"
    "global_load_dwordx4 %3, %7, off sc0 sc1\n\t"
    "s_waitcnt vmcnt(0)"
    : "=&v"(r0), "=&v"(r1), "=&v"(r2), "=&v"(r3)
    : "v"(p0), "v"(p1), "v"(p2), "v"(p3)
    : "memory");
}
__device__ __forceinline__ void st2_coh(bf16* p, bf16 v){
  u32 vv = (u32)__builtin_bit_cast(u16, v);
  asm volatile("global_store_short %0, %1, off sc0 sc1" :: "v"(p), "v"(vv) : "memory");
}

// ---- flag-array barrier: 32 slots/group, monotonic epochs, no RMW ----
// Arrival: block stores `target` to its own slot (parallel, fire-and-forget).
// Completion: wave 0 polls all 32 slots (lane i -> slot i&31; one coalesced
// 128B line fetch per iteration) until __all(slot >= target).
__device__ __forceinline__ void gbar3(u32* slots, int slot, u32 target, int lane){
  __syncthreads();
  if (threadIdx.x < 64){
    if (lane == 0){
      vdrain();                                     // my coherent stores at LLC
      __hip_atomic_store(slots + slot, target, __ATOMIC_RELAXED, SC);
    }
    u32 v = __hip_atomic_load(slots + (lane & 31), __ATOMIC_RELAXED, SC);
    while (!__all(v >= target)){
      __builtin_amdgcn_s_sleep(1);
      v = __hip_atomic_load(slots + (lane & 31), __ATOMIC_RELAXED, SC);
    }
  }
  __syncthreads();
}

// =================================================================
// Packing kernels (unchanged; validated).
// Fragment unit = 64 lanes x 8 bf16; lane's 8 elems =
//   W[row(j,lane&15)][kk*32 + ((lane>>4)&3)*8 + e]
// =================================================================
__global__ void pack_upper_k(const float* __restrict__ Wih, const float* __restrict__ Whh,
                             bf16* __restrict__ dst){
  int tid = blockIdx.x*256 + threadIdx.x;          // 1,048,576
  int lane = tid & 63;
  int u    = tid >> 6;
  int kk   = u & 31;
  int j    = (u >> 5) & 63;
  int s    = (u >> 11) & 3;
  int l    = u >> 13;
  int n    = j*16 + (lane & 15);
  int k    = kk*32 + ((lane>>4)&3)*8;
  int row  = (s==0) ? n : (s==1 ? 1024+n : 2048+n);
  size_t src = ((size_t)l*3072 + row)*1024 + k;
  size_t o = (size_t)tid*8;
  #pragma unroll
  for (int e=0;e<8;e++){
    float v;
    if (s < 2)      v = Wih[src+e] + Whh[src+e];
    else if (s==2)  v = Wih[src+e];
    else            v = Whh[src+e];
    dst[o+e] = f2bf(v);
  }
}
__global__ void pack_l0h_k(const float* __restrict__ Whh0, bf16* __restrict__ dst){
  int tid = blockIdx.x*256 + threadIdx.x;          // 393,216
  int lane = tid & 63;
  int u  = tid >> 6;
  int kk = u & 31;
  int j  = (u >> 5) & 63;
  int g  = u >> 11;
  int row = g*1024 + j*16 + (lane&15);
  int k   = kk*32 + ((lane>>4)&3)*8;
  size_t src = (size_t)row*1024 + k;
  size_t o = (size_t)tid*8;
  #pragma unroll
  for (int e=0;e<8;e++) dst[o+e] = f2bf(Whh0[src+e]);
}
__global__ void pack_l0x_k(const float* __restrict__ Wih0, bf16* __restrict__ dst){
  int tid = blockIdx.x*256 + threadIdx.x;          // 49,152
  int lane = tid & 63;
  int u  = tid >> 6;
  int kk = u & 3;
  int j  = (u >> 2) & 63;
  int g  = u >> 8;
  int row = g*1024 + j*16 + (lane&15);
  int k   = kk*32 + ((lane>>4)&3)*8;
  size_t src = (size_t)row*128 + k;
  size_t o = (size_t)tid*8;
  #pragma unroll
  for (int e=0;e<8;e++) dst[o+e] = f2bf(Wih0[src+e]);
}
__global__ void pack_imp_k(const float* __restrict__ Wp, bf16* __restrict__ dst){
  int tid = blockIdx.x*256 + threadIdx.x;          // 16,384
  int lane = tid & 63;
  int u  = tid >> 6;
  int kk = u & 31;
  int jj = u >> 5;
  int row = jj*16 + (lane&15);
  int k   = kk*32 + ((lane>>4)&3)*8;
  size_t src = (size_t)row*1024 + k;
  size_t o = (size_t)tid*8;
  #pragma unroll
  for (int e=0;e<8;e++) dst[o+e] = f2bf(Wp[src+e]);
}
__global__ void init_pk(u32* __restrict__ bar, bf16* __restrict__ h3){
  int tid = blockIdx.x*256 + threadIdx.x;          // 393,216
  if (tid < 1024) bar[tid] = 0u;
  h3[tid] = f2bf(0.f);                             // hA, hB, hC = 0
}

// =================================================================
// Staging: 32 rows x 1024 cols of h (row stride 1024) -> fragment-ordered
// LDS (64 KB). unit = kk*2 + half (kk=K-chunk 0..31, half=row half).
// chunk-in-unit = lane. Conflict-free ds_write/ds_read.
// =================================================================
__device__ __forceinline__ void stage_h(const bf16* __restrict__ src_rg, bf16* lds_h,
                                        int wave, int lane){
  const int sh = wave & 1, si = (wave >> 1) & 7;
  const int l15 = lane & 15, quad = lane >> 4;
  const bf16* g = src_rg + (size_t)(sh*16 + l15)*1024 + si*32 + quad*8;
  v4u r0,r1,r2,r3;
  ldx4_coh(g, g+256, g+512, g+768, r0,r1,r2,r3);
  bf16* d = lds_h + ((size_t)wave*64 + lane)*8;
  *(v4u*)(d)         = r0;
  *(v4u*)(d + 8192)  = r1;
  *(v4u*)(d + 16384) = r2;
  *(v4u*)(d + 24576) = r3;
}
// A-fragment from staged LDS: rows half*16+l15, K-chunk kk
__device__ __forceinline__ v8bf afrag(const bf16* lds_h, int kk, int ah, int lane){
  return ldv(lds_h + ((size_t)(kk*2+ah)*64 + lane)*8);
}
// scalar element (rl, colh) from staged LDS
__device__ __forceinline__ float hp_lds(const bf16* lds_h, int rl, int colh){
  int kk = colh >> 5, q = (colh >> 3) & 3, e = colh & 7;
  int ah = rl >> 4, lr = rl & 15;
  return bf2f(lds_h[((size_t)(kk*2+ah)*64 + q*16 + lr)*8 + e]);
}

#define MFMA(a,b,c) __builtin_amdgcn_mfma_f32_16x16x32_bf16((a),(b),(c),0,0,0)

// =================================================================
// Main persistent kernel: 128 blocks x 1024 threads (16 waves).
// bid: leaf=bid&7 (XCD affinity for weights), up=bid>>3: rg=up&3 (row group),
// jpair = leaf*4 + (up>>2)  (32 output cols; also the barrier slot id).
// 3 grid-barrier phases per step: L0 (with fused IC for step t-1), L1, L2.
// =================================================================
__global__ __launch_bounds__(1024, 4) void gru_pk(
  const float* __restrict__ x, const float* __restrict__ masks,
  const float* __restrict__ bih0, const float* __restrict__ bhh0,
  const float* __restrict__ bihR, const float* __restrict__ bhhR,
  const float* __restrict__ bp,
  const bf16* __restrict__ packU, const bf16* __restrict__ packL0h,
  const bf16* __restrict__ packL0x, const bf16* __restrict__ packImp,
  bf16* hA, bf16* hB, bf16* hC,
  u32* bar, float* out)
{
  const int tid  = threadIdx.x;
  const int lane = tid & 63;
  const int wave = tid >> 6;           // 0..15
  const int l15  = lane & 15;
  const int quad = lane >> 4;
  const int bid  = blockIdx.x;
  const int leaf = bid & 7;
  const int up   = bid >> 3;           // 0..15
  const int rg   = up & 3;             // row group
  const int jpair= leaf*4 + (up >> 2); // 0..31, unique within group
  const int rg32 = rg * 32;
  u32* slots = bar + rg*64;            // 32 flag slots (one 128B line)

  __shared__ bf16 lds_h[32768];        // 64 KB staged h slice
  __shared__ bf16 lds_c[4096];         // 8 KB staged comp slice
  __shared__ float lds2[18*512];       // 36 KB pre-activation partials
  u32 bc = 0;

  #pragma unroll 1
  for (int t = 0; t < 128; ++t){
    // ====== L0: fused IC(t-1) + hB = GRU0(input=comp(t-1), hidden=hA) ======
    {
      stage_h(hA + (size_t)rg32*1024, lds_h, wave, lane);
      __syncthreads();
      // ---- fused IC: build comp slice into lds_c ----
      if (t == 0){
        // comp(-1) = x[:, 0, :]
        if (wave < 8){
          const int sh = wave & 1, skk = wave >> 1;
          const float* g = x + (size_t)(rg32 + sh*16 + l15)*16384 + (size_t)skk*32 + quad*8;
          bf16* d = lds_c + ((size_t)wave*64 + lane)*8;
          #pragma unroll
          for (int e=0;e<8;e++) d[e] = f2bf(g[e]);
        }
      } else {
        // imp(t-1)[32,128] = lds_h(hA slice) @ Wp^T + bp, computed redundantly.
        // wave w -> output tile (ah = w&1 row half, dj = w>>1 col tile of 16)
        // 2 independent accumulators to halve the dependent-MFMA chain.
        const int ah = wave & 1, dj = wave >> 1;
        v4f acc0 = {0.f,0.f,0.f,0.f}, acc1 = {0.f,0.f,0.f,0.f};
        const bf16* wp = packImp + ((size_t)(dj*32))*512 + lane*8;
        #pragma unroll
        for (int kk=0;kk<32;kk+=2){
          acc0 = MFMA(afrag(lds_h, kk,   ah, lane), ldv(wp + (size_t)kk*512),     acc0);
          acc1 = MFMA(afrag(lds_h, kk+1, ah, lane), ldv(wp + (size_t)(kk+1)*512), acc1);
        }
        const v4f acc = acc0 + acc1;
        const int d   = dj*16 + l15;
        const int tm  = t - 1;
        const int kkc = d >> 5, qc = (d >> 3) & 3, ec = d & 7;
        bf16* cbase = lds_c + ((size_t)(kkc*2 + ah)*64 + qc*16)*8 + ec;
        const bool wr = ((d >> 2) == jpair);      // unique writer per 4 cols
        const float bpd = bp[d];
        #pragma unroll
        for (int r=0;r<4;r++){
          const int rl  = ah*16 + quad*4 + r;
          const int row = rg32 + rl;
          float imp = acc[r] + bpd;
          float m   = masks[row*128 + tm];
          float xv  = x[((size_t)row*128 + tm)*128 + d];
          float cv  = m*xv + (1.f - m)*imp;
          cbase[(size_t)(quad*4 + r)*8] = f2bf(cv);
          if (wr){
            size_t o = ((size_t)row*127 + tm)*128 + d;
            out[131072 + o]  = cv;    // completed
            out[2211840 + o] = imp;   // imputed
          }
        }
      }
      __syncthreads();
      // ---- main L0 matmuls ----
      if (wave < 12){
        const int g = wave % 3, jsub = (wave/3) & 1, ksec = wave/6;
        const int j = jpair*2 + jsub;
        v4f a0 = {0.f,0.f,0.f,0.f}, a1 = {0.f,0.f,0.f,0.f};
        const bf16* wp = packL0h + ((size_t)((g*64 + j)*32 + ksec*16))*512 + lane*8;
        #pragma unroll
        for (int i=0;i<16;++i){
          int kk = ksec*16 + i;
          v8bf wf = ldv(wp + (size_t)i*512);
          a0 = MFMA(afrag(lds_h, kk, 0, lane), wf, a0);
          a1 = MFMA(afrag(lds_h, kk, 1, lane), wf, a1);
        }
        #pragma unroll
        for (int r=0;r<4;r++){
          lds2[(wave*32 + quad*4 + r)*16 + l15]      = a0[r];
          lds2[(wave*32 + 16 + quad*4 + r)*16 + l15] = a1[r];
        }
      } else if (wave < 15){
        const int g = wave - 12;
        #pragma unroll
        for (int jsub=0;jsub<2;++jsub){
          const int j = jpair*2 + jsub;
          v4f a0 = {0.f,0.f,0.f,0.f}, a1 = {0.f,0.f,0.f,0.f};
          const bf16* wp = packL0x + ((size_t)((g*64 + j)*4))*512 + lane*8;
          #pragma unroll
          for (int i=0;i<4;++i){
            v8bf wf = ldv(wp + (size_t)i*512);
            a0 = MFMA(ldv(lds_c + ((size_t)(i*2+0)*64 + lane)*8), wf, a0);
            a1 = MFMA(ldv(lds_c + ((size_t)(i*2+1)*64 + lane)*8), wf, a1);
          }
          const int slot = 12 + g*2 + jsub;
          #pragma unroll
          for (int r=0;r<4;r++){
            lds2[(slot*32 + quad*4 + r)*16 + l15]      = a0[r];
            lds2[(slot*32 + 16 + quad*4 + r)*16 + l15] = a1[r];
          }
        }
      }
      __syncthreads();
      {
        const int rl = tid >> 5, c2 = tid & 31;
        const int jsub = c2 >> 4, c = c2 & 15;
        const int col = jpair*32 + c2;
        float ghr = lds2[((0+jsub*3)*32+rl)*16+c] + lds2[((6+jsub*3)*32+rl)*16+c];
        float ghz = lds2[((1+jsub*3)*32+rl)*16+c] + lds2[((7+jsub*3)*32+rl)*16+c];
        float ghn = lds2[((2+jsub*3)*32+rl)*16+c] + lds2[((8+jsub*3)*32+rl)*16+c];
        float gir = lds2[((12+jsub)*32+rl)*16+c];
        float giz = lds2[((14+jsub)*32+rl)*16+c];
        float gin = lds2[((16+jsub)*32+rl)*16+c];
        float rgg = sigm(gir + bih0[col]      + ghr + bhh0[col]);
        float zg  = sigm(giz + bih0[1024+col] + ghz + bhh0[1024+col]);
        float nv  = tanh_(gin + bih0[2048+col] + rgg*(ghn + bhh0[2048+col]));
        float hp  = hp_lds(lds_h, rl, col);
        st2_coh(hB + (size_t)(rg32+rl)*1024 + col, f2bf((1.f - zg)*nv + zg*hp));
        vdrain();
      }
      gbar3(slots, jpair, ++bc, lane);
    }

    // ================= L1 / L2: upper layers =================
    #pragma unroll 1
    for (int lay = 0; lay < 2; ++lay){
      const bf16* src = lay ? hC : hB;
      bf16*       dst = lay ? hA : hC;
      const bf16* packL = packU + (size_t)lay*4194304;
      const float* bi = bihR + lay*3072;
      const float* bh = bhhR + lay*3072;
      float* out_h = (lay == 1 && t == 127) ? out : nullptr;

      stage_h(src + (size_t)rg32*1024, lds_h, wave, lane);
      __syncthreads();
      {
        const int s = wave & 3, jsub = (wave>>2) & 1, ksec = wave >> 3;
        const int j = jpair*2 + jsub;
        v4f a0 = {0.f,0.f,0.f,0.f}, a1 = {0.f,0.f,0.f,0.f};
        const bf16* wp = packL + ((size_t)((s*64 + j)*32 + ksec*16))*512 + lane*8;
        #pragma unroll
        for (int i=0;i<16;++i){
          int kk = ksec*16 + i;
          v8bf wf = ldv(wp + (size_t)i*512);
          a0 = MFMA(afrag(lds_h, kk, 0, lane), wf, a0);
          a1 = MFMA(afrag(lds_h, kk, 1, lane), wf, a1);
        }
        #pragma unroll
        for (int r=0;r<4;r++){
          lds2[(wave*32 + quad*4 + r)*16 + l15]      = a0[r];
          lds2[(wave*32 + 16 + quad*4 + r)*16 + l15] = a1[r];
        }
      }
      __syncthreads();
      {
        const int rl = tid >> 5, c2 = tid & 31;
        const int jsub = c2 >> 4, c = c2 & 15;
        const int col = jpair*32 + c2;
        // slot(s,jsub,ksec) = s + jsub*4 + ksec*8
        float pr  = lds2[((0+jsub*4)*32+rl)*16+c] + lds2[((8+jsub*4)*32+rl)*16+c];
        float pz  = lds2[((1+jsub*4)*32+rl)*16+c] + lds2[((9+jsub*4)*32+rl)*16+c];
        float pin = lds2[((2+jsub*4)*32+rl)*16+c] + lds2[((10+jsub*4)*32+rl)*16+c];
        float phn = lds2[((3+jsub*4)*32+rl)*16+c] + lds2[((11+jsub*4)*32+rl)*16+c];
        float rgg = sigm(pr + bi[col] + bh[col]);
        float zg  = sigm(pz + bi[1024+col] + bh[1024+col]);
        float nv  = tanh_(pin + bi[2048+col] + rgg*(phn + bh[2048+col]));
        float hp  = hp_lds(lds_h, rl, col);
        float hv  = (1.f - zg)*nv + zg*hp;
        st2_coh(dst + (size_t)(rg32+rl)*1024 + col, f2bf(hv));
        if (out_h) out_h[(size_t)(rg32+rl)*1024 + col] = hv;
        vdrain();
      }
      gbar3(slots, jpair, ++bc, lane);
    }
  }
}

// ---------------- host ----------------
extern "C" void kernel_launch(void* const* d_in, const int* in_sizes, int n_in,
                              void* d_out, int out_size, void* d_ws, size_t ws_size,
                              hipStream_t stream)
{
  (void)in_sizes; (void)n_in; (void)out_size; (void)ws_size;
  const float* x     = (const float*)d_in[0];
  const float* masks = (const float*)d_in[1];
  const float* Wih0  = (const float*)d_in[2];
  const float* Whh0  = (const float*)d_in[3];
  const float* bih0  = (const float*)d_in[4];
  const float* bhh0  = (const float*)d_in[5];
  const float* WihR  = (const float*)d_in[6];
  const float* WhhR  = (const float*)d_in[7];
  const float* bihR  = (const float*)d_in[8];
  const float* bhhR  = (const float*)d_in[9];
  const float* Wp    = (const float*)d_in[10];
  const float* bp    = (const float*)d_in[11];
  float* out = (float*)d_out;

  // ws: bar u32[1024] | hA hB hC (bf16 131072 ea) | packed weights
  u32*  bar     = (u32*)d_ws;
  bf16* hA      = (bf16*)((char*)d_ws + 4096);
  bf16* hB      = hA + 131072;
  bf16* hC      = hB + 131072;
  bf16* packU   = hC + 131072;         // 8,388,608 elems
  bf16* packL0h = packU + 8388608;     // 3,145,728
  bf16* packL0x = packL0h + 3145728;   // 393,216
  bf16* packImp = packL0x + 393216;    // 131,072

  hipLaunchKernelGGL(init_pk,      dim3(1536), dim3(256), 0, stream, bar, hA);
  hipLaunchKernelGGL(pack_upper_k, dim3(4096), dim3(256), 0, stream, WihR, WhhR, packU);
  hipLaunchKernelGGL(pack_l0h_k,   dim3(1536), dim3(256), 0, stream, Whh0, packL0h);
  hipLaunchKernelGGL(pack_l0x_k,   dim3(192),  dim3(256), 0, stream, Wih0, packL0x);
  hipLaunchKernelGGL(pack_imp_k,   dim3(64),   dim3(256), 0, stream, Wp, packImp);
  hipLaunchKernelGGL(gru_pk,       dim3(128),  dim3(1024), 0, stream,
      x, masks, bih0, bhh0, bihR, bhhR, bp,
      packU, packL0h, packL0x, packImp, hA, hB, hC, bar, out);
}